// Round 1
// baseline (333.679 us; speedup 1.0000x reference)
//
#include <hip/hip_runtime.h>
#include <math.h>

#define NN 2048
#define CC 128
#define HH 8
#define DD 16
#define NKEY 128
#define INFV 1e8f

__device__ __forceinline__ float sigm(float x) { return 1.f / (1.f + expf(-x)); }

// ----------------------------------------------------------------------------
// Passthrough copy: atom_proj (N*C) then atom_pair (N*N*16) into d_out+N*C
// ----------------------------------------------------------------------------
__global__ void k_copy(const float4* __restrict__ proj, const float4* __restrict__ pair,
                       float4* __restrict__ dst) {
  const long npr = (long)NN * CC / 4;        // 65536
  const long ntot = npr + (long)NN * NN * 4; // + 16777216
  for (long i = (long)blockIdx.x * blockDim.x + threadIdx.x; i < ntot;
       i += (long)gridDim.x * blockDim.x) {
    dst[i] = (i < npr) ? proj[i] : pair[i - npr];
  }
}

// ----------------------------------------------------------------------------
// LN pass 1: ln_as = LN(atom_single); lnp = LN(atom_proj); s_ln_a = lnp*a_sln_w;
// s_ln_t = lnp*t_sln_w.  One wave per row, 2 channels per lane.
// ----------------------------------------------------------------------------
__global__ void k_ln1(const float* __restrict__ single, const float* __restrict__ proj,
                      const float* __restrict__ aslnw, const float* __restrict__ tslnw,
                      float* __restrict__ ln_as, float* __restrict__ s_ln_a,
                      float* __restrict__ s_ln_t) {
  int row = (blockIdx.x * blockDim.x + threadIdx.x) >> 6;
  int lane = threadIdx.x & 63;
  if (row >= NN) return;
  {
    float2 v = *(const float2*)(single + row * CC + lane * 2);
    float s = v.x + v.y, ss = v.x * v.x + v.y * v.y;
#pragma unroll
    for (int m = 1; m < 64; m <<= 1) { s += __shfl_xor(s, m); ss += __shfl_xor(ss, m); }
    float mu = s * (1.f / CC);
    float r = rsqrtf(ss * (1.f / CC) - mu * mu + 1e-5f);
    *(float2*)(ln_as + row * CC + lane * 2) = make_float2((v.x - mu) * r, (v.y - mu) * r);
  }
  {
    float2 v = *(const float2*)(proj + row * CC + lane * 2);
    float s = v.x + v.y, ss = v.x * v.x + v.y * v.y;
#pragma unroll
    for (int m = 1; m < 64; m <<= 1) { s += __shfl_xor(s, m); ss += __shfl_xor(ss, m); }
    float mu = s * (1.f / CC);
    float r = rsqrtf(ss * (1.f / CC) - mu * mu + 1e-5f);
    float y0 = (v.x - mu) * r, y1 = (v.y - mu) * r;
    float2 wa = *(const float2*)(aslnw + lane * 2);
    float2 wt = *(const float2*)(tslnw + lane * 2);
    *(float2*)(s_ln_a + row * CC + lane * 2) = make_float2(y0 * wa.x, y1 * wa.y);
    *(float2*)(s_ln_t + row * CC + lane * 2) = make_float2(y0 * wt.x, y1 * wt.y);
  }
}

// LN pass 2: ln_a2 = LN(single2)
__global__ void k_ln2(const float* __restrict__ x, float* __restrict__ y) {
  int row = (blockIdx.x * blockDim.x + threadIdx.x) >> 6;
  int lane = threadIdx.x & 63;
  if (row >= NN) return;
  float2 v = *(const float2*)(x + row * CC + lane * 2);
  float s = v.x + v.y, ss = v.x * v.x + v.y * v.y;
#pragma unroll
  for (int m = 1; m < 64; m <<= 1) { s += __shfl_xor(s, m); ss += __shfl_xor(ss, m); }
  float mu = s * (1.f / CC);
  float r = rsqrtf(ss * (1.f / CC) - mu * mu + 1e-5f);
  *(float2*)(y + row * CC + lane * 2) = make_float2((v.x - mu) * r, (v.y - mu) * r);
}

// ----------------------------------------------------------------------------
// Windowed pair bias: bias[h][q][kk] = LN(atom_pair[q, k(q,kk), :]) @ wz[:,h]
//                                      + mask_bias ; -INF for out-of-range k.
// One thread per (q,kk).
// ----------------------------------------------------------------------------
__global__ __launch_bounds__(256) void k_bias(const float* __restrict__ pair,
                                              const float* __restrict__ mask,
                                              const float* __restrict__ lnzw,
                                              const float* __restrict__ lnzb,
                                              const float* __restrict__ wz,
                                              float* __restrict__ bias) {
  __shared__ float swz[16 * HH], swn[16], sbn[16];
  int tid = threadIdx.x;
  if (tid < 128) swz[tid] = wz[tid];
  if (tid < 16) { swn[tid] = lnzw[tid]; sbn[tid] = lnzb[tid]; }
  __syncthreads();
  int e = blockIdx.x * 256 + tid; // 0..N*128-1
  int q = e >> 7, kk = e & 127;
  int k = (q >> 5) * 32 - 48 + kk;
  float out[HH];
  if (k >= 0 && k < NN) {
    const float4* p = (const float4*)(pair + ((long)q * NN + k) * 16);
    float4 x0 = p[0], x1 = p[1], x2 = p[2], x3 = p[3];
    float x[16] = {x0.x, x0.y, x0.z, x0.w, x1.x, x1.y, x1.z, x1.w,
                   x2.x, x2.y, x2.z, x2.w, x3.x, x3.y, x3.z, x3.w};
    float s = 0.f, ss = 0.f;
#pragma unroll
    for (int c = 0; c < 16; ++c) { s += x[c]; ss += x[c] * x[c]; }
    float mu = s * (1.f / 16.f);
    float r = rsqrtf(ss * (1.f / 16.f) - mu * mu + 1e-5f);
#pragma unroll
    for (int h = 0; h < HH; ++h) out[h] = 0.f;
#pragma unroll
    for (int c = 0; c < 16; ++c) {
      float y = (x[c] - mu) * r * swn[c] + sbn[c];
#pragma unroll
      for (int h = 0; h < HH; ++h) out[h] = fmaf(y, swz[c * HH + h], out[h]);
    }
    float mb = INFV * (mask[k] - 1.f);
#pragma unroll
    for (int h = 0; h < HH; ++h) out[h] += mb;
  } else {
#pragma unroll
    for (int h = 0; h < HH; ++h) out[h] = -INFV;
  }
#pragma unroll
  for (int h = 0; h < HH; ++h) bias[(long)h * NN * NKEY + e] = out[h];
}

// ----------------------------------------------------------------------------
// AdaLN GEMM (dual-B): out = sigmoid(A@B1 + b1) * lnm + A@B2
// A: N x 128, B1/B2: 128 x 128.  64x64 tile per block, 4x4 per thread, BK=64.
// ----------------------------------------------------------------------------
__global__ __launch_bounds__(256) void k_adaln(const float* __restrict__ A,
                                               const float* __restrict__ B1,
                                               const float* __restrict__ b1,
                                               const float* __restrict__ B2,
                                               const float* __restrict__ lnm,
                                               float* __restrict__ out) {
  __shared__ float As[64][68], B1s[64][68], B2s[64][68];
  int r0 = blockIdx.x * 64, c0 = blockIdx.y * 64;
  int tid = threadIdx.x;
  int tr = (tid >> 4) * 4, tc = (tid & 15) * 4;
  float acc1[4][4] = {{0}}, acc2[4][4] = {{0}};
  for (int kt = 0; kt < 2; ++kt) {
    int kb = kt * 64;
    __syncthreads();
    for (int i = tid; i < 64 * 64; i += 256) {
      int r = i >> 6, k = i & 63;
      As[k][r] = A[(r0 + r) * CC + kb + k];
    }
    for (int i = tid; i < 64 * 64; i += 256) {
      int k = i >> 6, c = i & 63;
      B1s[k][c] = B1[(kb + k) * CC + c0 + c];
      B2s[k][c] = B2[(kb + k) * CC + c0 + c];
    }
    __syncthreads();
    for (int k = 0; k < 64; ++k) {
      float4 a = *(const float4*)&As[k][tr];
      float4 p = *(const float4*)&B1s[k][tc];
      float4 qv = *(const float4*)&B2s[k][tc];
      float av[4] = {a.x, a.y, a.z, a.w};
      float pv[4] = {p.x, p.y, p.z, p.w};
      float qq[4] = {qv.x, qv.y, qv.z, qv.w};
#pragma unroll
      for (int i = 0; i < 4; ++i)
#pragma unroll
        for (int j = 0; j < 4; ++j) {
          acc1[i][j] = fmaf(av[i], pv[j], acc1[i][j]);
          acc2[i][j] = fmaf(av[i], qq[j], acc2[i][j]);
        }
    }
  }
#pragma unroll
  for (int i = 0; i < 4; ++i) {
    int r = r0 + tr + i;
    float4 lm = *(const float4*)(lnm + r * CC + c0 + tc);
    float lv[4] = {lm.x, lm.y, lm.z, lm.w};
    float o[4];
#pragma unroll
    for (int j = 0; j < 4; ++j)
      o[j] = sigm(acc1[i][j] + b1[c0 + tc + j]) * lv[j] + acc2[i][j];
    *(float4*)(out + r * CC + c0 + tc) = make_float4(o[0], o[1], o[2], o[3]);
  }
}

// ----------------------------------------------------------------------------
// QKVG GEMM: q = a@wq+bq, k = a@wk, v = a@wv, g = sigmoid(a@wg+bg)
// virtual N=512 cols; blockIdx.y selects matrix half.
// ----------------------------------------------------------------------------
__global__ __launch_bounds__(256) void k_gemm4(const float* __restrict__ A,
                                               const float* __restrict__ wq,
                                               const float* __restrict__ bq,
                                               const float* __restrict__ wk,
                                               const float* __restrict__ wv,
                                               const float* __restrict__ wg,
                                               const float* __restrict__ bg,
                                               float* __restrict__ qo, float* __restrict__ ko,
                                               float* __restrict__ vo, float* __restrict__ go) {
  __shared__ float As[64][68], Bs[64][68];
  int r0 = blockIdx.x * 64;
  int cg = blockIdx.y * 64;
  int mat = cg >> 7;
  int c0 = cg & 127;
  const float* B = (mat == 0) ? wq : (mat == 1) ? wk : (mat == 2) ? wv : wg;
  int tid = threadIdx.x;
  int tr = (tid >> 4) * 4, tc = (tid & 15) * 4;
  float acc[4][4] = {{0}};
  for (int kt = 0; kt < 2; ++kt) {
    int kb = kt * 64;
    __syncthreads();
    for (int i = tid; i < 64 * 64; i += 256) {
      int r = i >> 6, k = i & 63;
      As[k][r] = A[(r0 + r) * CC + kb + k];
    }
    for (int i = tid; i < 64 * 64; i += 256) {
      int k = i >> 6, c = i & 63;
      Bs[k][c] = B[(kb + k) * CC + c0 + c];
    }
    __syncthreads();
    for (int k = 0; k < 64; ++k) {
      float4 a = *(const float4*)&As[k][tr];
      float4 b = *(const float4*)&Bs[k][tc];
      float av[4] = {a.x, a.y, a.z, a.w};
      float bv[4] = {b.x, b.y, b.z, b.w};
#pragma unroll
      for (int i = 0; i < 4; ++i)
#pragma unroll
        for (int j = 0; j < 4; ++j) acc[i][j] = fmaf(av[i], bv[j], acc[i][j]);
    }
  }
  float* out = (mat == 0) ? qo : (mat == 1) ? ko : (mat == 2) ? vo : go;
#pragma unroll
  for (int i = 0; i < 4; ++i) {
    int r = r0 + tr + i;
    float o[4];
#pragma unroll
    for (int j = 0; j < 4; ++j) {
      float x = acc[i][j];
      if (mat == 0) x += bq[c0 + tc + j];
      if (mat == 3) x = sigm(x + bg[c0 + tc + j]);
      o[j] = x;
    }
    *(float4*)(out + r * CC + c0 + tc) = make_float4(o[0], o[1], o[2], o[3]);
  }
}

// ----------------------------------------------------------------------------
// Local attention per (window, head). 32 queries, 128 keys.
// og = (softmax(QK^T/4 + bias) @ V) * g
// ----------------------------------------------------------------------------
__global__ __launch_bounds__(256) void k_attn(const float* __restrict__ qm,
                                              const float* __restrict__ km,
                                              const float* __restrict__ vm,
                                              const float* __restrict__ gm,
                                              const float* __restrict__ bias,
                                              float* __restrict__ og) {
  int w = blockIdx.x;  // 0..63
  int h = blockIdx.y;  // 0..7
  int q0 = w * 32, k0 = w * 32 - 48;
  __shared__ float Qs[32][17];
  __shared__ float Ks[128][20];
  __shared__ float Vs[128][20];
  __shared__ float Ps[32][132];
  int tid = threadIdx.x;
  for (int i = tid; i < 32 * 16; i += 256) {
    int qi = i >> 4, d = i & 15;
    Qs[qi][d] = qm[(q0 + qi) * CC + h * DD + d];
  }
  for (int i = tid; i < 128 * 16; i += 256) {
    int kk = i >> 4, d = i & 15;
    int k = k0 + kk;
    bool ok = (k >= 0 && k < NN);
    Ks[kk][d] = ok ? km[k * CC + h * DD + d] : 0.f;
    Vs[kk][d] = ok ? vm[k * CC + h * DD + d] : 0.f;
  }
  __syncthreads();
  int qi = tid >> 3, kg = tid & 7;
  const float* brow = bias + (long)h * NN * NKEY + (long)(q0 + qi) * NKEY;
  float qreg[16];
#pragma unroll
  for (int d = 0; d < 16; ++d) qreg[d] = Qs[qi][d];
  float l[16];
#pragma unroll
  for (int j = 0; j < 16; ++j) {
    int kk = kg + 8 * j;
    const float4* kr = (const float4*)&Ks[kk][0];
    float4 kv0 = kr[0], kv1 = kr[1], kv2 = kr[2], kv3 = kr[3];
    float acc = 0.f;
    acc = fmaf(qreg[0], kv0.x, acc);  acc = fmaf(qreg[1], kv0.y, acc);
    acc = fmaf(qreg[2], kv0.z, acc);  acc = fmaf(qreg[3], kv0.w, acc);
    acc = fmaf(qreg[4], kv1.x, acc);  acc = fmaf(qreg[5], kv1.y, acc);
    acc = fmaf(qreg[6], kv1.z, acc);  acc = fmaf(qreg[7], kv1.w, acc);
    acc = fmaf(qreg[8], kv2.x, acc);  acc = fmaf(qreg[9], kv2.y, acc);
    acc = fmaf(qreg[10], kv2.z, acc); acc = fmaf(qreg[11], kv2.w, acc);
    acc = fmaf(qreg[12], kv3.x, acc); acc = fmaf(qreg[13], kv3.y, acc);
    acc = fmaf(qreg[14], kv3.z, acc); acc = fmaf(qreg[15], kv3.w, acc);
    l[j] = acc * 0.25f + brow[kk];
  }
  float m = l[0];
#pragma unroll
  for (int j = 1; j < 16; ++j) m = fmaxf(m, l[j]);
#pragma unroll
  for (int mm = 1; mm < 8; mm <<= 1) m = fmaxf(m, __shfl_xor(m, mm));
  float sum = 0.f;
#pragma unroll
  for (int j = 0; j < 16; ++j) { l[j] = expf(l[j] - m); sum += l[j]; }
#pragma unroll
  for (int mm = 1; mm < 8; mm <<= 1) sum += __shfl_xor(sum, mm);
  float inv = 1.f / sum;
#pragma unroll
  for (int j = 0; j < 16; ++j) Ps[qi][kg + 8 * j] = l[j] * inv;
  __syncthreads();
  int d0 = tid & 7;
  float o0 = 0.f, o1 = 0.f;
  for (int kk = 0; kk < 128; ++kk) {
    float p = Ps[qi][kk];
    o0 = fmaf(p, Vs[kk][d0], o0);
    o1 = fmaf(p, Vs[kk][d0 + 8], o1);
  }
  long base = (long)(q0 + qi) * CC + h * DD;
  og[base + d0] = o0 * gm[base + d0];
  og[base + d0 + 8] = o1 * gm[base + d0 + 8];
}

// ----------------------------------------------------------------------------
// out1: single2 = atom_single + sigmoid(proj@wog + bog) * (og@wo + bo)
// dual-A dual-B, K=128, BK=32.
// ----------------------------------------------------------------------------
__global__ __launch_bounds__(256) void k_out1(const float* __restrict__ ogm,
                                              const float* __restrict__ wo,
                                              const float* __restrict__ bo,
                                              const float* __restrict__ proj,
                                              const float* __restrict__ wog,
                                              const float* __restrict__ bog,
                                              const float* __restrict__ single,
                                              float* __restrict__ out) {
  __shared__ float A1s[32][68], B1s[32][68], A2s[32][68], B2s[32][68];
  int r0 = blockIdx.x * 64, c0 = blockIdx.y * 64;
  int tid = threadIdx.x;
  int tr = (tid >> 4) * 4, tc = (tid & 15) * 4;
  float accX[4][4] = {{0}}, accW[4][4] = {{0}};
  for (int kt = 0; kt < 4; ++kt) {
    int kb = kt * 32;
    __syncthreads();
    for (int i = tid; i < 32 * 64; i += 256) {
      int r = i >> 5, k = i & 31;
      A1s[k][r] = ogm[(r0 + r) * CC + kb + k];
      A2s[k][r] = proj[(r0 + r) * CC + kb + k];
    }
    for (int i = tid; i < 32 * 64; i += 256) {
      int k = i >> 6, c = i & 63;
      B1s[k][c] = wo[(kb + k) * CC + c0 + c];
      B2s[k][c] = wog[(kb + k) * CC + c0 + c];
    }
    __syncthreads();
    for (int k = 0; k < 32; ++k) {
      float4 a1 = *(const float4*)&A1s[k][tr];
      float4 b1 = *(const float4*)&B1s[k][tc];
      float4 a2 = *(const float4*)&A2s[k][tr];
      float4 b2 = *(const float4*)&B2s[k][tc];
      float a1v[4] = {a1.x, a1.y, a1.z, a1.w};
      float b1v[4] = {b1.x, b1.y, b1.z, b1.w};
      float a2v[4] = {a2.x, a2.y, a2.z, a2.w};
      float b2v[4] = {b2.x, b2.y, b2.z, b2.w};
#pragma unroll
      for (int i = 0; i < 4; ++i)
#pragma unroll
        for (int j = 0; j < 4; ++j) {
          accX[i][j] = fmaf(a1v[i], b1v[j], accX[i][j]);
          accW[i][j] = fmaf(a2v[i], b2v[j], accW[i][j]);
        }
    }
  }
#pragma unroll
  for (int i = 0; i < 4; ++i) {
    int r = r0 + tr + i;
    float4 sv = *(const float4*)(single + r * CC + c0 + tc);
    float s[4] = {sv.x, sv.y, sv.z, sv.w};
    float o[4];
#pragma unroll
    for (int j = 0; j < 4; ++j) {
      int c = c0 + tc + j;
      o[j] = s[j] + sigm(accW[i][j] + bog[c]) * (accX[i][j] + bo[c]);
    }
    *(float4*)(out + r * CC + c0 + tc) = make_float4(o[0], o[1], o[2], o[3]);
  }
}

// ----------------------------------------------------------------------------
// SwiGLU: hidden = silu(t@w_sw) * (t@w_hid).  B is 128x256 (ldb=256).
// ----------------------------------------------------------------------------
__global__ __launch_bounds__(256) void k_swiglu(const float* __restrict__ A,
                                                const float* __restrict__ Bsw,
                                                const float* __restrict__ Bhid,
                                                float* __restrict__ hidden) {
  __shared__ float As[64][68], B1s[64][68], B2s[64][68];
  int r0 = blockIdx.x * 64, c0 = blockIdx.y * 64;
  int tid = threadIdx.x;
  int tr = (tid >> 4) * 4, tc = (tid & 15) * 4;
  float acc1[4][4] = {{0}}, acc2[4][4] = {{0}};
  for (int kt = 0; kt < 2; ++kt) {
    int kb = kt * 64;
    __syncthreads();
    for (int i = tid; i < 64 * 64; i += 256) {
      int r = i >> 6, k = i & 63;
      As[k][r] = A[(r0 + r) * CC + kb + k];
    }
    for (int i = tid; i < 64 * 64; i += 256) {
      int k = i >> 6, c = i & 63;
      B1s[k][c] = Bsw[(kb + k) * 256 + c0 + c];
      B2s[k][c] = Bhid[(kb + k) * 256 + c0 + c];
    }
    __syncthreads();
    for (int k = 0; k < 64; ++k) {
      float4 a = *(const float4*)&As[k][tr];
      float4 p = *(const float4*)&B1s[k][tc];
      float4 qv = *(const float4*)&B2s[k][tc];
      float av[4] = {a.x, a.y, a.z, a.w};
      float pv[4] = {p.x, p.y, p.z, p.w};
      float qq[4] = {qv.x, qv.y, qv.z, qv.w};
#pragma unroll
      for (int i = 0; i < 4; ++i)
#pragma unroll
        for (int j = 0; j < 4; ++j) {
          acc1[i][j] = fmaf(av[i], pv[j], acc1[i][j]);
          acc2[i][j] = fmaf(av[i], qq[j], acc2[i][j]);
        }
    }
  }
#pragma unroll
  for (int i = 0; i < 4; ++i) {
    int r = r0 + tr + i;
    float o[4];
#pragma unroll
    for (int j = 0; j < 4; ++j) {
      float x = acc1[i][j];
      o[j] = x * sigm(x) * acc2[i][j];
    }
    *(float4*)(hidden + r * 256 + c0 + tc) = make_float4(o[0], o[1], o[2], o[3]);
  }
}

// ----------------------------------------------------------------------------
// out2: out = single2 + sigmoid(proj@t_wog + t_bog) * (hidden@w_out)
// K1=256 (hidden/w_out), K2=128 (proj/t_wog), BK=32.
// ----------------------------------------------------------------------------
__global__ __launch_bounds__(256) void k_out2(const float* __restrict__ hidden,
                                              const float* __restrict__ wout,
                                              const float* __restrict__ proj,
                                              const float* __restrict__ twog,
                                              const float* __restrict__ tbog,
                                              const float* __restrict__ single2,
                                              float* __restrict__ out) {
  __shared__ float A1s[32][68], B1s[32][68], A2s[32][68], B2s[32][68];
  int r0 = blockIdx.x * 64, c0 = blockIdx.y * 64;
  int tid = threadIdx.x;
  int tr = (tid >> 4) * 4, tc = (tid & 15) * 4;
  float accX[4][4] = {{0}}, accW[4][4] = {{0}};
  for (int kt = 0; kt < 8; ++kt) {
    int kb = kt * 32;
    __syncthreads();
    for (int i = tid; i < 32 * 64; i += 256) {
      int r = i >> 5, k = i & 31;
      A1s[k][r] = hidden[(r0 + r) * 256 + kb + k];
      if (kt < 4) A2s[k][r] = proj[(r0 + r) * CC + kb + k];
    }
    for (int i = tid; i < 32 * 64; i += 256) {
      int k = i >> 6, c = i & 63;
      B1s[k][c] = wout[(kb + k) * CC + c0 + c];
      if (kt < 4) B2s[k][c] = twog[(kb + k) * CC + c0 + c];
    }
    __syncthreads();
    if (kt < 4) {
      for (int k = 0; k < 32; ++k) {
        float4 a1 = *(const float4*)&A1s[k][tr];
        float4 b1 = *(const float4*)&B1s[k][tc];
        float4 a2 = *(const float4*)&A2s[k][tr];
        float4 b2 = *(const float4*)&B2s[k][tc];
        float a1v[4] = {a1.x, a1.y, a1.z, a1.w};
        float b1v[4] = {b1.x, b1.y, b1.z, b1.w};
        float a2v[4] = {a2.x, a2.y, a2.z, a2.w};
        float b2v[4] = {b2.x, b2.y, b2.z, b2.w};
#pragma unroll
        for (int i = 0; i < 4; ++i)
#pragma unroll
          for (int j = 0; j < 4; ++j) {
            accX[i][j] = fmaf(a1v[i], b1v[j], accX[i][j]);
            accW[i][j] = fmaf(a2v[i], b2v[j], accW[i][j]);
          }
      }
    } else {
      for (int k = 0; k < 32; ++k) {
        float4 a1 = *(const float4*)&A1s[k][tr];
        float4 b1 = *(const float4*)&B1s[k][tc];
        float a1v[4] = {a1.x, a1.y, a1.z, a1.w};
        float b1v[4] = {b1.x, b1.y, b1.z, b1.w};
#pragma unroll
        for (int i = 0; i < 4; ++i)
#pragma unroll
          for (int j = 0; j < 4; ++j) accX[i][j] = fmaf(a1v[i], b1v[j], accX[i][j]);
      }
    }
  }
#pragma unroll
  for (int i = 0; i < 4; ++i) {
    int r = r0 + tr + i;
    float4 sv = *(const float4*)(single2 + r * CC + c0 + tc);
    float s[4] = {sv.x, sv.y, sv.z, sv.w};
    float o[4];
#pragma unroll
    for (int j = 0; j < 4; ++j) {
      int c = c0 + tc + j;
      o[j] = s[j] + sigm(accW[i][j] + tbog[c]) * accX[i][j];
    }
    *(float4*)(out + r * CC + c0 + tc) = make_float4(o[0], o[1], o[2], o[3]);
  }
}

// ----------------------------------------------------------------------------
extern "C" void kernel_launch(void* const* d_in, const int* in_sizes, int n_in,
                              void* d_out, int out_size, void* d_ws, size_t ws_size,
                              hipStream_t stream) {
  (void)in_sizes; (void)n_in; (void)out_size; (void)ws_size;
  const float* atom_single = (const float*)d_in[0];
  const float* atom_proj   = (const float*)d_in[1];
  const float* atom_pair   = (const float*)d_in[2];
  const float* mask        = (const float*)d_in[3];
  const float* a_sln_w  = (const float*)d_in[4];
  const float* a_gate_w = (const float*)d_in[5];
  const float* a_gate_b = (const float*)d_in[6];
  const float* a_skip_w = (const float*)d_in[7];
  const float* wq = (const float*)d_in[8];
  const float* bq = (const float*)d_in[9];
  const float* wk = (const float*)d_in[10];
  const float* wv = (const float*)d_in[11];
  const float* wg = (const float*)d_in[12];
  const float* bg = (const float*)d_in[13];
  const float* wo = (const float*)d_in[14];
  const float* bo = (const float*)d_in[15];
  const float* lnz_w = (const float*)d_in[16];
  const float* lnz_b = (const float*)d_in[17];
  const float* wz    = (const float*)d_in[18];
  const float* wog = (const float*)d_in[19];
  const float* bog = (const float*)d_in[20];
  const float* t_sln_w  = (const float*)d_in[21];
  const float* t_gate_w = (const float*)d_in[22];
  const float* t_gate_b = (const float*)d_in[23];
  const float* t_skip_w = (const float*)d_in[24];
  const float* w_sw  = (const float*)d_in[25];
  const float* w_hid = (const float*)d_in[26];
  const float* w_out = (const float*)d_in[27];
  const float* t_wog = (const float*)d_in[28];
  const float* t_bog = (const float*)d_in[29];

  float* ws = (float*)d_ws;
  const long NC = (long)NN * CC; // 262144
  float* s_ln_a  = ws + 0 * NC;
  float* s_ln_t  = ws + 1 * NC;
  float* ln_as   = ws + 2 * NC;
  float* a_mat   = ws + 3 * NC;
  float* qm      = ws + 4 * NC;
  float* km      = ws + 5 * NC;
  float* vm      = ws + 6 * NC;
  float* gm      = ws + 7 * NC;
  float* ogm     = ws + 8 * NC;
  float* single2 = ws + 9 * NC;
  float* ln_a2   = ws + 10 * NC;
  float* t_mat   = ws + 11 * NC;
  float* hidden  = ws + 12 * NC;            // N*256 = 2*NC
  float* bias    = ws + 14 * NC;            // H*N*128 = 8*NC

  float* out = (float*)d_out;

  // Passthrough: atom_proj then atom_pair behind the computed output.
  k_copy<<<2048, 256, 0, stream>>>((const float4*)atom_proj, (const float4*)atom_pair,
                                   (float4*)(out + NC));

  k_ln1<<<512, 256, 0, stream>>>(atom_single, atom_proj, a_sln_w, t_sln_w,
                                 ln_as, s_ln_a, s_ln_t);
  k_bias<<<1024, 256, 0, stream>>>(atom_pair, mask, lnz_w, lnz_b, wz, bias);
  k_adaln<<<dim3(32, 2), 256, 0, stream>>>(s_ln_a, a_gate_w, a_gate_b, a_skip_w,
                                           ln_as, a_mat);
  k_gemm4<<<dim3(32, 8), 256, 0, stream>>>(a_mat, wq, bq, wk, wv, wg, bg,
                                           qm, km, vm, gm);
  k_attn<<<dim3(64, 8), 256, 0, stream>>>(qm, km, vm, gm, bias, ogm);
  k_out1<<<dim3(32, 2), 256, 0, stream>>>(ogm, wo, bo, atom_proj, wog, bog,
                                          atom_single, single2);
  k_ln2<<<512, 256, 0, stream>>>(single2, ln_a2);
  k_adaln<<<dim3(32, 2), 256, 0, stream>>>(s_ln_t, t_gate_w, t_gate_b, t_skip_w,
                                           ln_a2, t_mat);
  k_swiglu<<<dim3(32, 4), 256, 0, stream>>>(t_mat, w_sw, w_hid, hidden);
  k_out2<<<dim3(32, 2), 256, 0, stream>>>(hidden, w_out, atom_proj, t_wog, t_bog,
                                          single2, out);
}